// Round 6
// baseline (511.803 us; speedup 1.0000x reference)
//
#include <hip/hip_runtime.h>
#include <hip/hip_fp16.h>

#define N_DST 100000
#define DIN 128
#define HDIM 64
#define RREL 3
#define NE 1000000

#define NBKT_REL 196              // ceil(100000/512) buckets per relation
#define NBKT (RREL * NBKT_REL)    // 588 total buckets
#define NSEG (RREL * N_DST)       // 300000 segments
#define EDGE_CHUNK 16384
#define NBLK_BIN ((RREL * NE + EDGE_CHUNK - 1) / EDGE_CHUNK)  // 184

typedef _Float16 f16x8 __attribute__((ext_vector_type(8)));
typedef float f32x4 __attribute__((ext_vector_type(4)));

// ---------------- W prep: Wt [mat][k=128][n=64] f32 -> W16 fp16, transposed to
// [mat][col][k] and PRE-SWIZZLED (byte ^= (col&7)<<4 within the 256B col-row) so
// k_gemm stages it to LDS with a LINEAR copy and reads fragments with the same
// swizzled formula (conflict-free ds_read_b128). 128 KB once; ~5 us.
__global__ __launch_bounds__(256) void k_wprep(const float* __restrict__ Wt,
                                               __half* __restrict__ W16) {
  int g = blockIdx.x * 256 + threadIdx.x;  // 0..4095: [mat][kb][col], col fastest
  int col = g & 63;
  int kb = (g >> 6) & 15;   // 16B (8 fp16) granule along k
  int mat = g >> 10;
  const float* wp = Wt + ((size_t)mat * DIN + kb * 8) * HDIM + col;
  f16x8 hv;
#pragma unroll
  for (int j = 0; j < 8; j++) hv[j] = (_Float16)wp[(size_t)j * HDIM];
  *(f16x8*)((unsigned char*)W16 + mat * 16384 + col * 256 + ((kb * 16) ^ ((col & 7) << 4))) = hv;
}

// ---------------- GEMM via MFMA: h = A @ W + b  (4 matrices: dst + 3 relations) ----
// A is loaded DIRECTLY to registers (no LDS, no barrier on the A path): the
// 16x16x32 A-fragment layout (lane hi*16+li -> row li, k = ks*32+hi*8) makes the
// wave's fragment loads cover 16 rows x 128B contiguous -> fully coalesced.
// 2-deep ks software pipeline (8 dwordx4 in flight). W is staged from the
// pre-swizzled W16 via linear 16KB LDS copy. LDS 48KB -> 16KB.
// Epilogue: bias add + el/er logits via 16-lane xor-reduce; fp16 h store (rel mats).
__global__ __launch_bounds__(256) void k_gemm(
    const float* __restrict__ dst_feat, const float* __restrict__ neigh,
    const __half* __restrict__ W16, const float* __restrict__ bt,
    const float* __restrict__ attn_l, const float* __restrict__ attn_r,
    __half* __restrict__ h16, float* __restrict__ el, float* __restrict__ er) {
  const int RB = (N_DST + 127) / 128;  // 782 row-blocks per matrix
  int mat = blockIdx.x / RB;
  int row0 = (blockIdx.x % RB) * 128;
  const float* A = (mat == 0) ? dst_feat : (neigh + (size_t)(mat - 1) * N_DST * DIN);
  const float* b = bt + mat * HDIM;

  __shared__ __align__(16) unsigned char ldsW[16384];  // 64 cols x 128 k fp16 (swz)
  int tid = threadIdx.x;

  // ---- stage W16 (already fp16 + swizzled): linear 16KB copy ----
  {
    const float4* wsrc = (const float4*)((const unsigned char*)W16 + (size_t)mat * 16384);
#pragma unroll
    for (int i = 0; i < 4; i++)
      *(float4*)(ldsW + (tid + 256 * i) * 16) = wsrc[tid + 256 * i];
  }

  int w = tid >> 6;
  int l = tid & 63;
  int li = l & 15;   // fragment row/col within tile
  int hi = l >> 4;   // k-quarter within fragment

  // ---- A fragment pointers (rows clamped for the tail block) ----
  int r0 = row0 + w * 32 + li;
  int ra = min(r0, N_DST - 1);
  int rb = min(r0 + 16, N_DST - 1);
  const float* pa = A + (size_t)ra * DIN + hi * 8;
  const float* pb = A + (size_t)rb * DIN + hi * 8;

  auto cvt8 = [](const float4& v0, const float4& v1) {
    f16x8 h;
    h[0] = (_Float16)v0.x; h[1] = (_Float16)v0.y;
    h[2] = (_Float16)v0.z; h[3] = (_Float16)v0.w;
    h[4] = (_Float16)v1.x; h[5] = (_Float16)v1.y;
    h[6] = (_Float16)v1.z; h[7] = (_Float16)v1.w;
    return h;
  };

  // preload ks=0 and ks=1 (8 dwordx4 in flight)
  float4 sa0[2], sb0[2], sa1[2], sb1[2];
  sa0[0] = *(const float4*)(pa);      sa0[1] = *(const float4*)(pa + 4);
  sb0[0] = *(const float4*)(pb);      sb0[1] = *(const float4*)(pb + 4);
  sa1[0] = *(const float4*)(pa + 32); sa1[1] = *(const float4*)(pa + 36);
  sb1[0] = *(const float4*)(pb + 32); sb1[1] = *(const float4*)(pb + 36);

  __syncthreads();  // ldsW ready

  f32x4 acc[2][4] = {};
#define KS_STEP(KS, SA, SB, PREF_OFF, DO_PREF)                                  \
  {                                                                             \
    f16x8 afa = cvt8(SA[0], SA[1]);                                             \
    f16x8 afb = cvt8(SB[0], SB[1]);                                             \
    if (DO_PREF) {                                                              \
      SA[0] = *(const float4*)(pa + PREF_OFF);                                  \
      SA[1] = *(const float4*)(pa + PREF_OFF + 4);                              \
      SB[0] = *(const float4*)(pb + PREF_OFF);                                  \
      SB[1] = *(const float4*)(pb + PREF_OFF + 4);                              \
    }                                                                           \
    int kbyte = (KS)*64 + hi * 16;                                              \
    _Pragma("unroll") for (int ct = 0; ct < 4; ct++) {                          \
      int col = ct * 16 + li;                                                   \
      f16x8 bf = *(f16x8*)(ldsW + col * 256 + (kbyte ^ ((col & 7) << 4)));      \
      acc[0][ct] = __builtin_amdgcn_mfma_f32_16x16x32_f16(afa, bf, acc[0][ct], 0, 0, 0); \
      acc[1][ct] = __builtin_amdgcn_mfma_f32_16x16x32_f16(afb, bf, acc[1][ct], 0, 0, 0); \
    }                                                                           \
  }
  KS_STEP(0, sa0, sb0, 64, 1)   // prefetch ks=2 into slot 0
  KS_STEP(1, sa1, sb1, 96, 1)   // prefetch ks=3 into slot 1
  KS_STEP(2, sa0, sb0, 0, 0)
  KS_STEP(3, sa1, sb1, 0, 0)
#undef KS_STEP

  // ---- epilogue: bias, logits, fp16 h store ----
  // C/D layout: col = ct*16 + li, row(local) = w*32 + rt*16 + hi*4 + j
  float bv[4];
#pragma unroll
  for (int ct = 0; ct < 4; ct++) bv[ct] = b[ct * 16 + li];
#pragma unroll
  for (int rt = 0; rt < 2; rt++)
#pragma unroll
    for (int ct = 0; ct < 4; ct++)
#pragma unroll
      for (int j = 0; j < 4; j++) acc[rt][ct][j] += bv[ct];

  if (mat == 0) {
    // er[r][n] = h_dst[n] . attn_r[r]
#pragma unroll
    for (int r = 0; r < RREL; r++) {
      float av[4];
#pragma unroll
      for (int ct = 0; ct < 4; ct++) av[ct] = attn_r[r * HDIM + ct * 16 + li];
#pragma unroll
      for (int rt = 0; rt < 2; rt++) {
        float p[4];
#pragma unroll
        for (int j = 0; j < 4; j++)
          p[j] = acc[rt][0][j] * av[0] + acc[rt][1][j] * av[1] +
                 acc[rt][2][j] * av[2] + acc[rt][3][j] * av[3];
#pragma unroll
        for (int o = 1; o < 16; o <<= 1)
#pragma unroll
          for (int j = 0; j < 4; j++) p[j] += __shfl_xor(p[j], o);
        if (li == 0) {
#pragma unroll
          for (int j = 0; j < 4; j++) {
            int gr = row0 + w * 32 + rt * 16 + hi * 4 + j;
            if (gr < N_DST) er[r * N_DST + gr] = p[j];
          }
        }
      }
    }
  } else {
    int r = mat - 1;
    float av[4];
#pragma unroll
    for (int ct = 0; ct < 4; ct++) av[ct] = attn_l[r * HDIM + ct * 16 + li];
#pragma unroll
    for (int rt = 0; rt < 2; rt++) {
      float p[4];
#pragma unroll
      for (int j = 0; j < 4; j++)
        p[j] = acc[rt][0][j] * av[0] + acc[rt][1][j] * av[1] +
               acc[rt][2][j] * av[2] + acc[rt][3][j] * av[3];
#pragma unroll
      for (int o = 1; o < 16; o <<= 1)
#pragma unroll
        for (int j = 0; j < 4; j++) p[j] += __shfl_xor(p[j], o);
      if (li == 0) {
#pragma unroll
        for (int j = 0; j < 4; j++) {
          int gr = row0 + w * 32 + rt * 16 + hi * 4 + j;
          if (gr < N_DST) el[r * N_DST + gr] = p[j];
        }
      }
    }
    __half* hb = h16 + (size_t)r * N_DST * HDIM;
#pragma unroll
    for (int rt = 0; rt < 2; rt++)
#pragma unroll
      for (int j = 0; j < 4; j++) {
        int gr = row0 + w * 32 + rt * 16 + hi * 4 + j;
        if (gr < N_DST) {
#pragma unroll
          for (int ct = 0; ct < 4; ct++)
            hb[(size_t)gr * HDIM + ct * 16 + li] = __float2half(acc[rt][ct][j]);
        }
      }
  }
}

// ---------------- CSR build: counting-sort partition, zero global atomics ----------------
// Buckets: (relation, dst>>9) -> 588 buckets of 512 dst nodes; bucket order == segment order.

// 1) per-chunk histogram -> hist[bucket][block] (bucket-major)
__global__ __launch_bounds__(256) void k_hist(const int* __restrict__ dst_idx,
                                              int* __restrict__ hist) {
  __shared__ int h[NBKT];
  int tid = threadIdx.x;
  int blk = blockIdx.x;
  for (int i = tid; i < NBKT; i += 256) h[i] = 0;
  __syncthreads();
  int e0 = blk * EDGE_CHUNK;
  int e1 = min(e0 + EDGE_CHUNK, RREL * NE);
  for (int idx = e0 + tid; idx < e1; idx += 256) {
    int r = idx / NE;
    int d = dst_idx[idx];
    atomicAdd(&h[r * NBKT_REL + (d >> 9)], 1);
  }
  __syncthreads();
  for (int i = tid; i < NBKT; i += 256)
    hist[(size_t)i * NBLK_BIN + blk] = h[i];
}

// 2) per-bucket exclusive scan across blocks; bucket totals out
__global__ __launch_bounds__(256) void k_colscan(int* __restrict__ hist,
                                                 int* __restrict__ bcounts) {
  __shared__ int sm[256];
  int b = blockIdx.x;
  int tid = threadIdx.x;
  int v = (tid < NBLK_BIN) ? hist[(size_t)b * NBLK_BIN + tid] : 0;
  sm[tid] = v;
  __syncthreads();
  for (int off = 1; off < 256; off <<= 1) {
    int t = (tid >= off) ? sm[tid - off] : 0;
    __syncthreads();
    sm[tid] += t;
    __syncthreads();
  }
  if (tid < NBLK_BIN) hist[(size_t)b * NBLK_BIN + tid] = sm[tid] - v;  // exclusive
  if (tid == 255) bcounts[b] = sm[255];
}

// 3) scan 588 bucket totals -> bucket_base[589]; offsets[NSEG]=3M
__global__ __launch_bounds__(256) void k_bscan(const int* __restrict__ bcounts,
                                               int* __restrict__ bucket_base,
                                               int* __restrict__ offsets) {
  __shared__ int sm[256];
  int tid = threadIdx.x;
  int base = tid * 3;
  int c[3];
#pragma unroll
  for (int k = 0; k < 3; k++) c[k] = (base + k < NBKT) ? bcounts[base + k] : 0;
  int tsum = c[0] + c[1] + c[2];
  sm[tid] = tsum;
  __syncthreads();
  for (int off = 1; off < 256; off <<= 1) {
    int v = (tid >= off) ? sm[tid - off] : 0;
    __syncthreads();
    sm[tid] += v;
    __syncthreads();
  }
  int run = sm[tid] - tsum;
#pragma unroll
  for (int k = 0; k < 3; k++) {
    if (base + k < NBKT) bucket_base[base + k] = run;
    run += c[k];
  }
  if (tid == 255) bucket_base[NBKT] = sm[255];  // = RREL*NE
  if (tid == 0) offsets[NSEG] = RREL * NE;
}

// 4) place edges: per-block LDS cursors seeded from scanned bases; LDS atomics only.
//    Packed word (localdst<<17 | src); src < 2^17, localdst < 2^9.
__global__ __launch_bounds__(256) void k_place(const int* __restrict__ src_idx,
                                               const int* __restrict__ dst_idx,
                                               const int* __restrict__ hist,
                                               const int* __restrict__ bucket_base,
                                               unsigned* __restrict__ tmp) {
  __shared__ int cur[NBKT];
  int tid = threadIdx.x;
  int blk = blockIdx.x;
  for (int i = tid; i < NBKT; i += 256)
    cur[i] = bucket_base[i] + hist[(size_t)i * NBLK_BIN + blk];
  __syncthreads();
  int e0 = blk * EDGE_CHUNK;
  int e1 = min(e0 + EDGE_CHUNK, RREL * NE);
  for (int idx = e0 + tid; idx < e1; idx += 256) {
    int r = idx / NE;
    int d = dst_idx[idx];
    int s = src_idx[idx];
    int bucket = r * NBKT_REL + (d >> 9);
    int pos = atomicAdd(&cur[bucket], 1);
    tmp[pos] = ((unsigned)(d & 511) << 17) | (unsigned)s;
  }
}

// 5) per-bucket: LDS histogram of 512 local segments + block scan -> per-segment
//    offsets + final scatter (random writes confined to ~20 KB -> L2-combined).
__global__ __launch_bounds__(256) void k_bucket_csr(
    const int* __restrict__ bucket_base, const unsigned* __restrict__ tmp,
    int* __restrict__ src_sorted, int* __restrict__ offsets) {
  __shared__ int cnt[512];
  __shared__ int base_l[512];
  __shared__ int sm[256];
  int b = blockIdx.x;
  int r = b / NBKT_REL;
  int brel = b - r * NBKT_REL;
  int gbase = bucket_base[b];
  int gend = bucket_base[b + 1];
  int tid = threadIdx.x;
  cnt[tid] = 0;
  cnt[tid + 256] = 0;
  __syncthreads();
  for (int e = gbase + tid; e < gend; e += 256)
    atomicAdd(&cnt[tmp[e] >> 17], 1);
  __syncthreads();
  int c0 = cnt[2 * tid], c1 = cnt[2 * tid + 1];
  int tsum = c0 + c1;
  sm[tid] = tsum;
  __syncthreads();
  for (int off = 1; off < 256; off <<= 1) {
    int v = (tid >= off) ? sm[tid - off] : 0;
    __syncthreads();
    sm[tid] += v;
    __syncthreads();
  }
  int run = sm[tid] - tsum;
  base_l[2 * tid] = run;
  base_l[2 * tid + 1] = run + c0;
  __syncthreads();
  for (int s = tid; s < 512; s += 256) {
    int dst = (brel << 9) + s;
    if (dst < N_DST) offsets[r * N_DST + dst] = gbase + base_l[s];
    cnt[s] = 0;
  }
  __syncthreads();
  for (int e = gbase + tid; e < gend; e += 256) {
    unsigned w = tmp[e];
    int s = w >> 17;
    int pos = gbase + base_l[s] + atomicAdd(&cnt[s], 1);
    src_sorted[pos] = (int)(w & 0x1FFFFu);
  }
}

// ---------------- GAT aggregation: 8 lanes per (relation, dst-node) ----------------
// Shuffle-free: each 8-lane group owns one segment; lane li owns dims 8li..8li+7
// (16B of the fp16 row -> 128B group load per edge). All 8 lanes redundantly
// compute the edge weight from broadcast loads (same addr in group -> L1
// broadcast), so ssum is replicated (no reduce) and accumulators are final
// (no cross-group combine, no divergent store). 8 nodes per wave amortizes
// prologue/epilogue 8x vs the old wave-per-node scheme (~36 instr/edge -> ~7).
__global__ __launch_bounds__(256) void k_aggregate(
    const int* __restrict__ offsets, const int* __restrict__ src_sorted,
    const float* __restrict__ el, const float* __restrict__ er,
    const __half* __restrict__ h16, float* __restrict__ zbuf) {
  int gw = blockIdx.x * 32 + (threadIdx.x >> 3);
  int li = threadIdx.x & 7;  // lane-in-group: dims 8*li .. 8*li+7
  if (gw >= NSEG) return;
  int r = gw / N_DST;
  int start = offsets[gw], end = offsets[gw + 1];
  float erv = er[gw];
  const unsigned char* hs = (const unsigned char*)(h16 + (size_t)r * N_DST * HDIM);
  const float* elr = el + (size_t)r * N_DST;
  float acc[8] = {};
  float ssum = 0.f;
  int sNext = (start < end) ? src_sorted[start] : 0;  // 1-deep index prefetch
  for (int e = start; e < end; ++e) {
    int s = sNext;
    if (e + 1 < end) sNext = src_sorted[e + 1];
    float x = elr[s] + erv;                     // broadcast gather (L2-resident)
    float4 rv = *(const float4*)(hs + (unsigned)(s * 128 + li * 16));
    x = (x > 0.f) ? x : 0.01f * x;              // leaky_relu
    float a = __expf(x);
    ssum += a;
    const __half2* hp = (const __half2*)&rv;
#pragma unroll
    for (int q = 0; q < 4; q++) {
      float2 f = __half22float2(hp[q]);
      acc[2 * q] += a * f.x;
      acc[2 * q + 1] += a * f.y;
    }
  }
  float inv = (end > start) ? 1.f / ssum : 0.f;
  float zv[8];
#pragma unroll
  for (int q = 0; q < 8; q++) {
    float v = acc[q] * inv;
    zv[q] = (v > 0.f) ? v : (__expf(v) - 1.f);  // elu; empty segment -> elu(0)=0
  }
  float* zp = zbuf + (size_t)gw * HDIM + li * 8;
  *(float4*)zp = make_float4(zv[0], zv[1], zv[2], zv[3]);
  *(float4*)(zp + 4) = make_float4(zv[4], zv[5], zv[6], zv[7]);
}

// ---------------- semantic attention reduce (MFMA) ----------------
// z(128 rows x 64) @ W1(64 x 128) on matrix cores, fp16 inputs / f32 accum.
// Both operands staged fp16 in XOR-swizzled LDS (byte ^= (row&7)<<4, stride 128B).
// Epilogue: x+b1 -> tanh -> *w2, xor-reduce over the 16 col-lanes, guarded
// LDS wsum atomics (128-row blocks straddle the relation boundary).
__global__ __launch_bounds__(256) void k_semantic(
    const float* __restrict__ zbuf, const float* __restrict__ W1,
    const float* __restrict__ b1, const float* __restrict__ w2,
    float* __restrict__ w_acc) {
  __shared__ __align__(16) unsigned char lds[32 * 1024];
  unsigned char* ldsZ = lds;           // 128 rows x 64 k fp16 (stride 128B, swz)
  unsigned char* ldsW = lds + 16384;   // 128 cols x 64 k fp16 (stride 128B, swz)
  __shared__ float wsum[RREL];
  int tid = threadIdx.x;
  if (tid < RREL) wsum[tid] = 0.f;
  int row0 = blockIdx.x * 128;

  // ---- stage W1: [k=64][n=128] f32 -> [col][k] fp16 (coalesced k-row reads) ----
  {
    int col = tid & 127;
    int kq = tid >> 7;  // 0..1 (k chunk of 32)
    const float* wp = W1 + (size_t)(kq * 32) * 128 + col;
    float wr[32];
#pragma unroll
    for (int m = 0; m < 32; m++) wr[m] = wp[(size_t)m * 128];
#pragma unroll
    for (int m8 = 0; m8 < 4; m8++) {
      f16x8 hv;
#pragma unroll
      for (int j = 0; j < 8; j++) hv[j] = (_Float16)wr[m8 * 8 + j];
      int byt = kq * 64 + m8 * 16;  // = k*2
      *(f16x8*)(ldsW + col * 128 + (byt ^ ((col & 7) << 4))) = hv;
    }
  }
  // ---- stage z: 128 rows x 64 f32 -> fp16 [row][k] swizzled ----
#pragma unroll
  for (int i = 0; i < 4; i++) {
    int s = tid + 256 * i;  // 0..1023
    int row = s >> 3;       // 0..127
    int kb = s & 7;         // 16B (8 fp16) chunk along k
    int gr = row0 + row;
    if (gr >= NSEG) gr = NSEG - 1;  // clamp (tail; guarded at atomicAdd)
    const float* zp = zbuf + (size_t)gr * HDIM + kb * 8;
    float4 v0 = *(const float4*)zp;
    float4 v1 = *(const float4*)(zp + 4);
    f16x8 hv;
    hv[0] = (_Float16)v0.x; hv[1] = (_Float16)v0.y;
    hv[2] = (_Float16)v0.z; hv[3] = (_Float16)v0.w;
    hv[4] = (_Float16)v1.x; hv[5] = (_Float16)v1.y;
    hv[6] = (_Float16)v1.z; hv[7] = (_Float16)v1.w;
    *(f16x8*)(ldsZ + row * 128 + ((kb * 16) ^ ((row & 7) << 4))) = hv;
  }
  __syncthreads();

  // ---- MFMA: wave w owns rows w*32..w*32+31 (2 M-tiles) x 128 cols (8 N-tiles) ----
  int w = tid >> 6;
  int l = tid & 63;
  int li = l & 15;  // col within tile
  int hi = l >> 4;  // k-quarter / row-quarter
  f32x4 acc[2][8] = {};
#pragma unroll
  for (int ks = 0; ks < 2; ks++) {
    int kbyte = ks * 64 + hi * 16;
    f16x8 af[2], bf[8];
#pragma unroll
    for (int rt = 0; rt < 2; rt++) {
      int row = w * 32 + rt * 16 + li;
      af[rt] = *(f16x8*)(ldsZ + row * 128 + (kbyte ^ ((row & 7) << 4)));
    }
#pragma unroll
    for (int ct = 0; ct < 8; ct++) {
      int col = ct * 16 + li;
      bf[ct] = *(f16x8*)(ldsW + col * 128 + (kbyte ^ ((col & 7) << 4)));
    }
#pragma unroll
    for (int rt = 0; rt < 2; rt++)
#pragma unroll
      for (int ct = 0; ct < 8; ct++)
        acc[rt][ct] = __builtin_amdgcn_mfma_f32_16x16x32_f16(af[rt], bf[ct], acc[rt][ct], 0, 0, 0);
  }

  // ---- epilogue: tanh(x+b1) . w2, reduce over cols ----
  // C/D layout: col = ct*16 + li, row(local) = w*32 + rt*16 + hi*4 + j
  float p[2][4] = {};
#pragma unroll
  for (int ct = 0; ct < 8; ct++) {
    float b1v = b1[ct * 16 + li];
    float w2v = w2[ct * 16 + li];
#pragma unroll
    for (int rt = 0; rt < 2; rt++)
#pragma unroll
      for (int j = 0; j < 4; j++) {
        float x = acc[rt][ct][j] + b1v;
        float ex = __expf(2.f * x);
        p[rt][j] += (1.f - 2.f / (ex + 1.f)) * w2v;  // tanh
      }
  }
#pragma unroll
  for (int o = 1; o < 16; o <<= 1)
#pragma unroll
    for (int rt = 0; rt < 2; rt++)
#pragma unroll
      for (int j = 0; j < 4; j++) p[rt][j] += __shfl_xor(p[rt][j], o);
  if (li == 0) {
#pragma unroll
    for (int rt = 0; rt < 2; rt++)
#pragma unroll
      for (int j = 0; j < 4; j++) {
        int row = row0 + w * 32 + rt * 16 + hi * 4 + j;
        if (row < NSEG) atomicAdd(&wsum[row / N_DST], p[rt][j]);
      }
  }
  __syncthreads();
  if (tid < RREL) atomicAdd(&w_acc[tid], wsum[tid]);
}

// ---------------- softmax over relations + weighted combine ----------------
__global__ __launch_bounds__(256) void k_final(const float* __restrict__ zbuf,
                                               const float* __restrict__ w_acc,
                                               float* __restrict__ out) {
  int idx = blockIdx.x * 256 + threadIdx.x;
  if (idx >= N_DST * HDIM / 4) return;
  const float invN = 1.0f / N_DST;
  float w0 = w_acc[0] * invN, w1 = w_acc[1] * invN, w2v = w_acc[2] * invN;
  float m = fmaxf(w0, fmaxf(w1, w2v));
  float e0 = __expf(w0 - m), e1 = __expf(w1 - m), e2 = __expf(w2v - m);
  float inv = 1.f / (e0 + e1 + e2);
  e0 *= inv; e1 *= inv; e2 *= inv;
  size_t o = (size_t)idx * 4;
  const size_t stride = (size_t)N_DST * HDIM;
  float4 z0 = *(const float4*)(zbuf + o);
  float4 z1 = *(const float4*)(zbuf + stride + o);
  float4 z2 = *(const float4*)(zbuf + 2 * stride + o);
  float4 r;
  r.x = e0 * z0.x + e1 * z1.x + e2 * z2.x;
  r.y = e0 * z0.y + e1 * z1.y + e2 * z2.y;
  r.z = e0 * z0.z + e1 * z1.z + e2 * z2.z;
  r.w = e0 * z0.w + e1 * z1.w + e2 * z2.w;
  *(float4*)(out + o) = r;
}

extern "C" void kernel_launch(void* const* d_in, const int* in_sizes, int n_in,
                              void* d_out, int out_size, void* d_ws, size_t ws_size,
                              hipStream_t stream) {
  const float* dst_feat = (const float*)d_in[0];
  const float* neigh = (const float*)d_in[1];
  const float* Wt = (const float*)d_in[2];
  const float* bt = (const float*)d_in[3];
  const float* attn_l = (const float*)d_in[4];
  const float* attn_r = (const float*)d_in[5];
  const float* W1 = (const float*)d_in[6];
  const float* b1 = (const float*)d_in[7];
  const float* w2 = (const float*)d_in[8];
  const int* src_idx = (const int*)d_in[9];
  const int* dst_idx = (const int*)d_in[10];
  float* out = (float*)d_out;

  char* p = (char*)d_ws;
  auto alloc = [&](size_t bytes) {
    char* q = p;
    p += (bytes + 255) & ~(size_t)255;
    return (void*)q;
  };
  __half* h16 = (__half*)alloc((size_t)RREL * N_DST * HDIM * 2);
  __half* W16 = (__half*)alloc((size_t)(RREL + 1) * HDIM * DIN * 2);  // 64 KB
  float* el = (float*)alloc((size_t)RREL * N_DST * 4);
  float* er = (float*)alloc((size_t)RREL * N_DST * 4);
  float* zbuf = (float*)alloc((size_t)RREL * N_DST * HDIM * 4);
  float* w_acc = (float*)alloc(64);
  int* offsets = (int*)alloc(((size_t)NSEG + 1) * 4);
  int* hist = (int*)alloc((size_t)NBKT * NBLK_BIN * 4);
  int* bcounts = (int*)alloc((size_t)NBKT * 4);
  int* bucket_base = (int*)alloc((size_t)(NBKT + 1) * 4);
  unsigned* tmp = (unsigned*)alloc((size_t)RREL * NE * 4);
  int* src_sorted = (int*)alloc((size_t)RREL * NE * 4);

  hipMemsetAsync(w_acc, 0, 64, stream);

  k_wprep<<<16, 256, 0, stream>>>(Wt, W16);
  k_gemm<<<4 * ((N_DST + 127) / 128), 256, 0, stream>>>(dst_feat, neigh, W16, bt, attn_l, attn_r,
                                                        h16, el, er);
  k_hist<<<NBLK_BIN, 256, 0, stream>>>(dst_idx, hist);
  k_colscan<<<NBKT, 256, 0, stream>>>(hist, bcounts);
  k_bscan<<<1, 256, 0, stream>>>(bcounts, bucket_base, offsets);
  k_place<<<NBLK_BIN, 256, 0, stream>>>(src_idx, dst_idx, hist, bucket_base, tmp);
  k_bucket_csr<<<NBKT, 256, 0, stream>>>(bucket_base, tmp, src_sorted, offsets);
  k_aggregate<<<(NSEG + 31) / 32, 256, 0, stream>>>(offsets, src_sorted, el, er, h16, zbuf);
  k_semantic<<<(NSEG + 127) / 128, 256, 0, stream>>>(zbuf, W1, b1, w2, w_acc);
  k_final<<<(N_DST * HDIM / 4 + 255) / 256, 256, 0, stream>>>(zbuf, w_acc, out);
}